// Round 15
// baseline (141.252 us; speedup 1.0000x reference)
//
#include <hip/hip_runtime.h>
#include <hip/hip_bf16.h>
#include <stdint.h>
#include <stddef.h>

#define S_LEN 2048
#define DMODEL 1024
#define NHEAD 16
#define HDIM 64
#define BATCH 2
#define MROWS (BATCH * S_LEN) /* 4096 */
#define QK_LD 2048            /* qkv buffer holds q|k only */

typedef unsigned short u16;
typedef __attribute__((ext_vector_type(8))) short bf16x8;
typedef __attribute__((ext_vector_type(4))) short bf16x4;
typedef __attribute__((ext_vector_type(4))) float f32x4;

__device__ inline u16 f32_to_bf16(float f) {
  union { float f; unsigned int u; } v; v.f = f;
  unsigned int u = v.u;
  unsigned int r = (u + 0x7fffu + ((u >> 16) & 1u)) >> 16;
  return (u16)r;
}

__device__ inline void gload16(const u16* g, u16* l) {
  __builtin_amdgcn_global_load_lds(
      (const __attribute__((address_space(1))) unsigned int*)g,
      (__attribute__((address_space(3))) unsigned int*)l, 16, 0, 0);
}

// ---------------- fused prologue: conv + window + W-transpose ----------------
__global__ __launch_bounds__(256) void prep(const float* __restrict__ x, u16* __restrict__ xb,
                                            const float* __restrict__ alpha, int* __restrict__ halfw,
                                            const float* __restrict__ Wq, const float* __restrict__ Wk,
                                            const float* __restrict__ Wv, u16* __restrict__ Wt) {
  __shared__ float lds[32 * 33]; // 4224 B
  const int bid = blockIdx.x, tid = threadIdx.x;

  if (bid < 2048) {
    size_t i = ((size_t)bid * 256 + tid) * 8;
    float4 v0 = *(const float4*)(x + i);
    float4 v1 = *(const float4*)(x + i + 4);
    bf16x8 r;
    r[0] = (short)f32_to_bf16(v0.x); r[1] = (short)f32_to_bf16(v0.y);
    r[2] = (short)f32_to_bf16(v0.z); r[3] = (short)f32_to_bf16(v0.w);
    r[4] = (short)f32_to_bf16(v1.x); r[5] = (short)f32_to_bf16(v1.y);
    r[6] = (short)f32_to_bf16(v1.z); r[7] = (short)f32_to_bf16(v1.w);
    *(bf16x8*)(xb + i) = r;
  } else if (bid == 2048) {
    float s = 0.f;
    for (int i = tid; i < BATCH * DMODEL; i += 256) {
      int b = i >> 10, d = i & 1023;
      size_t base = (size_t)b * S_LEN * DMODEL + d;
      float f1 = x[base + (size_t)(S_LEN - 1) * DMODEL];
      float f0 = x[base + (size_t)(S_LEN - 2) * DMODEL];
      s += fabsf(f1 - f0);
    }
#pragma unroll
    for (int m = 32; m >= 1; m >>= 1) s += __shfl_xor(s, m, 64);
    if ((tid & 63) == 0) lds[tid >> 6] = s;
    __syncthreads();
    if (tid == 0) {
      float total = lds[0] + lds[1] + lds[2] + lds[3];
      float mean = total / (float)(BATCH * DMODEL);
      float e1 = x[(size_t)(S_LEN - 1) * DMODEL];
      float e0 = x[(size_t)(S_LEN - 2) * DMODEL];
      float ew = fabsf(e1 - e0);
      float a = 1.f / (1.f + expf(-alpha[0]));
      float sig = a * mean + (1.f - a) * ew;
      float scale = 1.f / (1.f + expf(-sig));
      int wv = (int)floorf(24.f + 96.f * scale);
      *halfw = wv >> 1;
    }
  } else {
    float (*tile)[33] = (float (*)[33])lds;
    const int r = bid - 2049;
    const int z = r >> 10, rem = r & 1023;
    const int k0 = (rem >> 5) * 32, n0 = (rem & 31) * 32;
    const float* W = z == 0 ? Wq : (z == 1 ? Wk : Wv);
    const int tx = tid & 31, ty = tid >> 5;
#pragma unroll
    for (int i = 0; i < 4; ++i)
      tile[ty + i * 8][tx] = W[(size_t)(k0 + ty + i * 8) * DMODEL + n0 + tx];
    __syncthreads();
    u16* o = Wt + (size_t)z * DMODEL * DMODEL;
#pragma unroll
    for (int i = 0; i < 4; ++i)
      o[(size_t)(n0 + ty + i * 8) * DMODEL + k0 + tx] = f32_to_bf16(tile[tx][ty + i * 8]);
  }
}

// ---------------- QKV GEMM (blocks 0..767) + fused Wc build (blocks 768..831) ----------------
// GEMM: m97-faithful 128x128, single 32KB buffer, 3 blocks/CU (best of 8 variants R2-R13).
// Wc blocks: zero-LDS streaming (Wfc coalesced single-use reads; W_o wave-uniform scalar);
// acc[64] fits the (256,3) ~170-VGPR budget (R5's spill was the 44-VGPR low-LDS budget).
// Wc_t is only consumed by gemm_fc, so concurrent execution with the GEMM is safe.
__global__ __launch_bounds__(256, 3) void gemm_qkv(
    const u16* __restrict__ A, const u16* __restrict__ Bt,
    const float* __restrict__ bq, const float* __restrict__ bk,
    const float* __restrict__ bv, u16* __restrict__ out, u16* __restrict__ vt,
    const float* __restrict__ W_o, const float* __restrict__ Wfc,
    u16* __restrict__ Wc_t) {
  __shared__ __align__(16) u16 smem[128 * 64 * 2]; // 32 KiB: A | B

  const int tid = threadIdx.x;

  if (blockIdx.x >= 768) {
    // ---- Wc = blockdiag(W_o) @ Wfc, stored transposed bf16 [N][K] ----
    const int idx2 = blockIdx.x - 768;     // 0..63
    const int n0 = (idx2 & 3) * 256;
    const int h = idx2 >> 2;
    const int col = n0 + tid;
    float acc[64];
#pragma unroll
    for (int d = 0; d < 64; ++d) acc[d] = 0.f;
#pragma unroll 4
    for (int c = 0; c < 64; ++c) {
      float wv = Wfc[(size_t)(h * 64 + c) * DMODEL + col];
#pragma unroll
      for (int d = 0; d < 64; ++d)
        acc[d] += W_o[(size_t)(h * 64 + d) * 64 + c] * wv;
    }
    u16 tmp[64];
#pragma unroll
    for (int d = 0; d < 64; ++d) tmp[d] = f32_to_bf16(acc[d]);
    u16* dst = Wc_t + (size_t)col * DMODEL + h * 64;
#pragma unroll
    for (int q = 0; q < 8; ++q)
      *(bf16x8*)(dst + q * 8) = *(bf16x8*)(tmp + q * 8);
    return;
  }

  const int l = tid & 63, w = tid >> 6;   // 4 waves, 2x2
  const int wr = w >> 1, wc = w & 1;
  const int lrow = l & 15, lk = l >> 4;

  const int xcd = blockIdx.x & 7;
  const int idx = blockIdx.x >> 3;        // 0..95
  const int bm = idx & 31;
  const int bn = xcd * 3 + (idx >> 5);
  const int rowA0 = bm * 128;
  const int colB0 = bn * 128;

  f32x4 acc[4][4] = {};
  u16* As = smem;
  u16* Bs = smem + 128 * 64;

#pragma unroll 1
  for (int t = 0; t < 16; ++t) {
    const int kt = t * 64;
#pragma unroll
    for (int i = 0; i < 4; ++i) {
      int c = i * 256 + tid;
      int row = c >> 3, u = c & 7;
      const u16* g = A + (size_t)(rowA0 + row) * DMODEL + kt + ((u ^ (row & 7)) << 3);
      gload16(g, As + c * 8);
    }
#pragma unroll
    for (int i = 0; i < 4; ++i) {
      int c = i * 256 + tid;
      int row = c >> 3, u = c & 7;
      const u16* g = Bt + (size_t)(colB0 + row) * DMODEL + kt + ((u ^ (row & 7)) << 3);
      gload16(g, Bs + c * 8);
    }
    asm volatile("s_waitcnt vmcnt(0)");
    __syncthreads();
#pragma unroll
    for (int kk = 0; kk < 2; ++kk) {
      const int swz = ((((kk << 2) + lk) ^ (lrow & 7)) << 3);
      bf16x8 af[4], bg[4];
#pragma unroll
      for (int m = 0; m < 4; ++m)
        af[m] = *(const bf16x8*)(As + (wr * 64 + m * 16 + lrow) * 64 + swz);
#pragma unroll
      for (int n = 0; n < 4; ++n)
        bg[n] = *(const bf16x8*)(Bs + (wc * 64 + n * 16 + lrow) * 64 + swz);
#pragma unroll
      for (int m = 0; m < 4; ++m)
#pragma unroll
        for (int n = 0; n < 4; ++n)
          acc[m][n] = __builtin_amdgcn_mfma_f32_16x16x32_bf16(af[m], bg[n], acc[m][n], 0, 0, 0);
    }
    __syncthreads();
  }

  // epilogue: cols <2048 -> q|k (q scaled 1/8); cols >=2048 -> vT[b][d][s]
#pragma unroll
  for (int n = 0; n < 4; ++n) {
    int c = colB0 + wc * 64 + n * 16 + lrow;   // 0..3071
    if (c < 2048) {
      float bias = (c < 1024) ? bq[c] : bk[c - 1024];
      float mult = (c < 1024) ? 0.125f : 1.0f;
#pragma unroll
      for (int m = 0; m < 4; ++m) {
        int r0 = rowA0 + wr * 64 + m * 16 + lk * 4;
#pragma unroll
        for (int j = 0; j < 4; ++j)
          out[(size_t)(r0 + j) * QK_LD + c] = f32_to_bf16((acc[m][n][j] + bias) * mult);
      }
    } else {
      const int dfull = c - 2048;
      const float bias = bv[dfull];
#pragma unroll
      for (int m = 0; m < 4; ++m) {
        int r0 = rowA0 + wr * 64 + m * 16 + lk * 4;
        int bb = r0 >> 11, s = r0 & 2047;
        bf16x4 p;
#pragma unroll
        for (int j = 0; j < 4; ++j) p[j] = (short)f32_to_bf16(acc[m][n][j] + bias);
        *(bf16x4*)(vt + ((size_t)bb << 21) + (size_t)dfull * 2048 + s) = p;
      }
    }
  }
}

// ---------------- final FC GEMM: 64x128 tile, single 24KB buffer, 2 blocks/CU ----------------
__global__ __launch_bounds__(256, 2) void gemm_fc(const u16* __restrict__ A,
                                                  const u16* __restrict__ Bt,
                                                  const float* __restrict__ bias,
                                                  float* __restrict__ out) {
  __shared__ __align__(16) u16 smem[(64 + 128) * 64]; // 24 KiB: A | B

  const int tid = threadIdx.x;
  const int l = tid & 63, w = tid >> 6;
  const int wr = w >> 1, wc = w & 1;      // wave tile 32x64
  const int lrow = l & 15, lk = l >> 4;

  const int bn = blockIdx.x & 7;
  const int bm = blockIdx.x >> 3;         // 0..63
  const int rowA0 = bm * 64, colB0 = bn * 128;

  f32x4 acc[2][4] = {};
  u16* As = smem;
  u16* Bs = smem + 64 * 64;

#pragma unroll 1
  for (int t = 0; t < 16; ++t) {
    const int kt = t * 64;
#pragma unroll
    for (int i = 0; i < 2; ++i) {
      int c = i * 256 + tid;
      int row = c >> 3, u = c & 7;
      const u16* g = A + (size_t)(rowA0 + row) * DMODEL + kt + ((u ^ (row & 7)) << 3);
      gload16(g, As + c * 8);
    }
#pragma unroll
    for (int i = 0; i < 4; ++i) {
      int c = i * 256 + tid;
      int row = c >> 3, u = c & 7;
      const u16* g = Bt + (size_t)(colB0 + row) * DMODEL + kt + ((u ^ (row & 7)) << 3);
      gload16(g, Bs + c * 8);
    }
    asm volatile("s_waitcnt vmcnt(0)");
    __syncthreads();
#pragma unroll
    for (int kk = 0; kk < 2; ++kk) {
      const int swz = ((((kk << 2) + lk) ^ (lrow & 7)) << 3);
      bf16x8 af[2], bg[4];
#pragma unroll
      for (int m = 0; m < 2; ++m)
        af[m] = *(const bf16x8*)(As + (wr * 32 + m * 16 + lrow) * 64 + swz);
#pragma unroll
      for (int n = 0; n < 4; ++n)
        bg[n] = *(const bf16x8*)(Bs + (wc * 64 + n * 16 + lrow) * 64 + swz);
#pragma unroll
      for (int m = 0; m < 2; ++m)
#pragma unroll
        for (int n = 0; n < 4; ++n)
          acc[m][n] = __builtin_amdgcn_mfma_f32_16x16x32_bf16(af[m], bg[n], acc[m][n], 0, 0, 0);
    }
    __syncthreads();
  }

#pragma unroll
  for (int n = 0; n < 4; ++n) {
    int c = colB0 + wc * 64 + n * 16 + lrow;
    float bv = bias[c];
#pragma unroll
    for (int m = 0; m < 2; ++m) {
      int r0 = rowA0 + wr * 32 + m * 16 + lk * 4;
#pragma unroll
      for (int j = 0; j < 4; ++j)
        out[(size_t)(r0 + j) * DMODEL + c] = acc[m][n][j] + bv;
    }
  }
}

// ---------------- banded attention: swapped-QK softmax (R14, verified) ----------------
__global__ __launch_bounds__(256) void attn_win(const u16* __restrict__ qkv,
                                                const u16* __restrict__ vt,
                                                u16* __restrict__ ao,
                                                const int* __restrict__ halfptr) {
  __shared__ __align__(16) u16 KP[12800];  // K [192][64] swizzled; reused as P [64][200]
  __shared__ __align__(16) u16 Vs[12800];  // V^T [64 d][200 key-padded]
  const int tid = threadIdx.x, l = tid & 63, w = tid >> 6;
  const int lrow = l & 15, lk = l >> 4;
  const int q0 = blockIdx.x * 64, k0 = q0 - 64;
  const int h = blockIdx.y, b = blockIdx.z;
  const int halfw = *halfptr;
  const int f_lo = (64 - halfw) >> 4;
  const int f_hi = (127 + halfw) >> 4;

  const u16* qb = qkv;
  const u16* kb = qkv + 1024;

#pragma unroll
  for (int i = 0; i < 6; ++i) {
    int c = i * 256 + tid;
    int row = c >> 3, u = c & 7;
    const u16* g = kb + (ptrdiff_t)((b * S_LEN + k0 + row) * QK_LD + h * 64 + ((u ^ (row & 7)) << 3));
    gload16(g, KP + c * 8);
  }
  const int qrow = q0 + w * 16 + lrow;
  bf16x8 qf[2];
#pragma unroll
  for (int kk = 0; kk < 2; ++kk)
    qf[kk] = *(const bf16x8*)(qb + (ptrdiff_t)((b * S_LEN + qrow) * QK_LD + h * 64 + kk * 32 + lk * 8));
#pragma unroll
  for (int i = 0; i < 6; ++i) {
    int o = i * 256 + tid;
    int d = o / 25, ch = o - d * 25;
    int kc = k0 + ch * 8;
    kc = kc < 0 ? 0 : (kc > 2040 ? 2040 : kc);
    const u16* g = vt + ((size_t)b << 21) + (size_t)(h * 64 + d) * 2048 + kc;
    gload16(g, Vs + o * 8);
  }
  {
    int o = 1536 + tid;
    if (o < 1600) {
      int d = o / 25, ch = o - d * 25;
      int kc = k0 + ch * 8;
      kc = kc < 0 ? 0 : (kc > 2040 ? 2040 : kc);
      const u16* g = vt + ((size_t)b << 21) + (size_t)(h * 64 + d) * 2048 + kc;
      gload16(g, Vs + o * 8);
    }
  }

  asm volatile("s_waitcnt vmcnt(6)" ::: "memory");   // K landed; V in flight
  __builtin_amdgcn_s_barrier();
  asm volatile("" ::: "memory");

  // swapped QK^T: sc[f][j] = S[k = k0+f*16+lk*4+j][q = qrow]
  f32x4 sc[12];
#pragma unroll
  for (int f = 0; f < 12; ++f) sc[f] = (f32x4){0.f, 0.f, 0.f, 0.f};
#pragma unroll
  for (int kk = 0; kk < 2; ++kk) {
#pragma unroll
    for (int f = 0; f < 12; ++f) {
      if (f >= f_lo && f <= f_hi) {
        bf16x8 kf = *(const bf16x8*)(KP + (f * 16 + lrow) * 64 + ((((kk << 2) + lk) ^ (lrow & 7)) << 3));
        sc[f] = __builtin_amdgcn_mfma_f32_16x16x32_bf16(kf, qf[kk], sc[f], 0, 0, 0);
      }
    }
  }

  // mask + softmax (one query per lane)
  const int qi = qrow;
  float rmax = -3e38f;
#pragma unroll
  for (int f = 0; f < 12; ++f) {
    if (f < f_lo || f > f_hi) continue;
#pragma unroll
    for (int j = 0; j < 4; ++j) {
      int kj = k0 + f * 16 + lk * 4 + j;
      bool kok = (kj >= 0) && (kj < S_LEN);
      int dd = qi - kj;
      int ad = dd < 0 ? -dd : dd;
      float v = (kok && ad <= halfw) ? sc[f][j] : -1e30f;
      sc[f][j] = v;
      rmax = fmaxf(rmax, v);
    }
  }
  rmax = fmaxf(rmax, __shfl_xor(rmax, 16, 64));
  rmax = fmaxf(rmax, __shfl_xor(rmax, 32, 64));
  float rsum = 0.f;
#pragma unroll
  for (int f = 0; f < 12; ++f) {
    if (f < f_lo || f > f_hi) continue;
#pragma unroll
    for (int j = 0; j < 4; ++j) {
      float e = __expf(sc[f][j] - rmax);
      sc[f][j] = e;
      rsum += e;
    }
  }
  rsum += __shfl_xor(rsum, 16, 64);
  rsum += __shfl_xor(rsum, 32, 64);
  const float rinv = 1.0f / rsum;

  __builtin_amdgcn_s_barrier();   // all KP reads done -> reuse as P
  asm volatile("" ::: "memory");

  u16* Ps = KP;
  const int prow = w * 16 + lrow;
#pragma unroll
  for (int f = 0; f < 12; ++f) {
    bf16x4 p;
    if (f < f_lo || f > f_hi) {
      p[0] = p[1] = p[2] = p[3] = 0;
    } else {
#pragma unroll
      for (int j = 0; j < 4; ++j) p[j] = (short)f32_to_bf16(sc[f][j] * rinv);
    }
    *(bf16x4*)(Ps + prow * 200 + f * 16 + lk * 4) = p;
  }
  asm volatile("s_waitcnt lgkmcnt(0) vmcnt(0)" ::: "memory");  // P written, V landed
  __builtin_amdgcn_s_barrier();
  asm volatile("" ::: "memory");

  f32x4 o[4] = {};
#pragma unroll
  for (int jt = 0; jt < 6; ++jt) {
    bf16x8 pa = *(const bf16x8*)(Ps + (w * 16 + lrow) * 200 + jt * 32 + lk * 8);
#pragma unroll
    for (int n = 0; n < 4; ++n) {
      bf16x8 vf = *(const bf16x8*)(Vs + (n * 16 + lrow) * 200 + jt * 32 + lk * 8);
      o[n] = __builtin_amdgcn_mfma_f32_16x16x32_bf16(pa, vf, o[n], 0, 0, 0);
    }
  }
#pragma unroll
  for (int n = 0; n < 4; ++n)
#pragma unroll
    for (int j = 0; j < 4; ++j) {
      int qi2 = q0 + w * 16 + lk * 4 + j;
      int d = n * 16 + lrow;
      ao[(size_t)(b * S_LEN + qi2) * DMODEL + h * 64 + d] = f32_to_bf16(o[n][j]);
    }
}

// ---------------- launch ----------------
extern "C" void kernel_launch(void* const* d_in, const int* in_sizes, int n_in,
                              void* d_out, int out_size, void* d_ws, size_t ws_size,
                              hipStream_t stream) {
  (void)in_sizes; (void)n_in; (void)out_size; (void)ws_size;
  const float* x     = (const float*)d_in[0];
  const float* alpha = (const float*)d_in[1];
  const float* Wq    = (const float*)d_in[2];
  const float* bq    = (const float*)d_in[3];
  const float* Wk    = (const float*)d_in[4];
  const float* bk    = (const float*)d_in[5];
  const float* Wv    = (const float*)d_in[6];
  const float* bv    = (const float*)d_in[7];
  const float* W_o   = (const float*)d_in[8];
  const float* Wfc   = (const float*)d_in[9];
  const float* bfc   = (const float*)d_in[10];

  char* ws = (char*)d_ws;
  int* halfw  = (int*)ws;
  u16* xb     = (u16*)(ws + 256);
  u16* Wqkv_t = xb + (size_t)MROWS * DMODEL;
  u16* qkv    = Wqkv_t + (size_t)3 * DMODEL * DMODEL;    // [4096][2048] q|k
  u16* vt     = qkv + (size_t)MROWS * QK_LD;             // [2][1024][2048]
  u16* ao     = vt + (size_t)BATCH * DMODEL * S_LEN;
  u16* Wc_t   = ao + (size_t)MROWS * DMODEL;

  hipLaunchKernelGGL(prep, dim3(5121), dim3(256), 0, stream,
                     x, xb, alpha, halfw, Wq, Wk, Wv, Wqkv_t);
  hipLaunchKernelGGL(gemm_qkv, dim3(832), dim3(256), 0, stream,
                     xb, Wqkv_t, bq, bk, bv, qkv, vt, W_o, Wfc, Wc_t);
  hipLaunchKernelGGL(attn_win, dim3(S_LEN / 64, NHEAD, BATCH), dim3(256), 0, stream,
                     qkv, vt, ao, halfw);
  hipLaunchKernelGGL(gemm_fc, dim3(512), dim3(256), 0, stream,
                     ao, Wc_t, bfc, (float*)d_out);
}